// Round 4
// baseline (551.475 us; speedup 1.0000x reference)
//
#include <hip/hip_runtime.h>

#define NN 16
#define SS 16384
#define VV 256
#define TT ((long)NN * SS)   // 262144 tokens
#define NC 47                // total codes (padded to 48 for MFMA)

static constexpr int CB_SIZES_H[10] = {3, 5, 5, 5, 5, 3, 7, 8, 3, 3};
static constexpr int CB_OFF_H[10]   = {0, 3, 8, 13, 18, 23, 26, 33, 41, 44};

typedef float v4f    __attribute__((ext_vector_type(4)));
typedef float f32x4  __attribute__((ext_vector_type(4)));
typedef short short8 __attribute__((ext_vector_type(8)));
typedef unsigned uint4e __attribute__((ext_vector_type(4)));

// ---------------------------------------------------------------------------
// Precompute (verified r2/r3). su[k][n] = -2*(W1_g^T e_c)[k] split into bf16
// hi/lo in MFMA B-fragment order; biasv; proj.
// ---------------------------------------------------------------------------
__global__ __launch_bounds__(256) void vq_pre(
    const float* __restrict__ W1, const float* __restrict__ b1,
    const float* __restrict__ W2,
    const float* __restrict__ cb0, const float* __restrict__ cb1,
    const float* __restrict__ cb2, const float* __restrict__ cb3,
    const float* __restrict__ cb4, const float* __restrict__ cb5,
    const float* __restrict__ cb6, const float* __restrict__ cb7,
    const float* __restrict__ cb8, const float* __restrict__ cb9,
    unsigned short* __restrict__ bfrag, float* __restrict__ biasv,
    float* __restrict__ proj)
{
    const int gc = blockIdx.x;           // 0..47 (47 = zero pad column)
    const int v  = threadIdx.x;          // 0..255 = k
    const int ks = v >> 5, kl = v & 31, h = kl >> 3, j = kl & 7;

    if (gc >= NC) {                      // pad column: zeros
        const int idx = (ks * 3 + 2) * 512 + (h * 16 + 15) * 8 + j;
        bfrag[idx] = 0;
        bfrag[12288 + idx] = 0;
        return;
    }

    const float* cbs[10] = {cb0, cb1, cb2, cb3, cb4, cb5, cb6, cb7, cb8, cb9};
    int g = 0;
    #pragma unroll
    for (int gg = 1; gg < 10; gg++) if (gc >= CB_OFF_H[gg]) g = gg;
    const int c = gc - CB_OFF_H[g];
    const float* e = cbs[g] + c * 16;

    float su = 0.f, pj = 0.f;
    #pragma unroll
    for (int i = 0; i < 16; i++)
        su = fmaf(W1[(long)(16 * g + i) * VV + v], e[i], su);
    const float s2 = -2.f * su;

    const unsigned u = __builtin_bit_cast(unsigned, s2);
    const float r = s2 - __builtin_bit_cast(float, u & 0xFFFF0000u);
    unsigned t = __builtin_bit_cast(unsigned, r);
    t += 0x7FFFu + ((t >> 16) & 1u);
    const int idx = (ks * 3 + (gc >> 4)) * 512 + (h * 16 + (gc & 15)) * 8 + j;
    bfrag[idx]         = (unsigned short)(u >> 16);
    bfrag[12288 + idx] = (unsigned short)(t >> 16);

    #pragma unroll
    for (int i = 0; i < 16; i++)
        pj = fmaf(e[i], W2[(long)v * 160 + i * 10 + g], pj);
    proj[gc * VV + v] = pj;

    if (v == 0) {
        float b = 0.f;
        #pragma unroll
        for (int i = 0; i < 16; i++)
            b += e[i] * (e[i] - 2.f * b1[16 * g + i]);
        biasv[gc] = b;
    }
}

// ---------------------------------------------------------------------------
static __device__ __forceinline__ void cvt_hi_lo(
    const float4 f0, const float4 f1, short8& ah, short8& al)
{
    const float f[8] = {f0.x, f0.y, f0.z, f0.w, f1.x, f1.y, f1.z, f1.w};
    uint4e H, L;
    #pragma unroll
    for (int p = 0; p < 4; p++) {
        const unsigned u0 = __builtin_bit_cast(unsigned, f[2 * p]);
        const unsigned u1 = __builtin_bit_cast(unsigned, f[2 * p + 1]);
        H[p] = (u0 >> 16) | (u1 & 0xFFFF0000u);
        const float r0 = f[2 * p]     - __builtin_bit_cast(float, u0 & 0xFFFF0000u);
        const float r1 = f[2 * p + 1] - __builtin_bit_cast(float, u1 & 0xFFFF0000u);
        unsigned t0 = __builtin_bit_cast(unsigned, r0);
        unsigned t1 = __builtin_bit_cast(unsigned, r1);
        t0 += 0x7FFFu + ((t0 >> 16) & 1u);
        t1 += 0x7FFFu + ((t1 >> 16) & 1u);
        L[p] = (t0 >> 16) | (t1 & 0xFFFF0000u);
    }
    ah = __builtin_bit_cast(short8, H);
    al = __builtin_bit_cast(short8, L);
}

static __device__ __forceinline__ unsigned argmin_pack(const float* acc) {
    unsigned p = 0;
    #pragma unroll
    for (int g = 0; g < 10; g++) {
        const int off = CB_OFF_H[g];
        const int k = CB_SIZES_H[g];
        float best = acc[off];
        int bi = 0;
        #pragma unroll
        for (int c = 1; c < 8; c++) {
            if (c < k) {
                const float vv = acc[off + c];
                if (vv < best) { best = vv; bi = c; }  // strict <: np first-min
            }
        }
        p |= (unsigned)bi << (3 * g);
    }
    return p;
}

// ---------------------------------------------------------------------------
// Fused kernel. Block = 256 threads / 256 tokens.
//
// LDS (50176 B union, three sequential uses, barrier-separated):
//   [phase 1 ] bfrag copy (49152 B) -- B fragments, read via ds_read_b128
//   [phase 1b] scan slabs float[4][64][49]
//   [phase 2 ] proj v4f[NC*64]
//
// Phase 1 is BARRIER-FREE: A fragments are loaded global->VGPR with an
// explicit ping-pong prefetch at half-ks granularity (fully unrolled -> SSA,
// scheduler can pipeline loads arbitrarily deep; no vmcnt(0) drains).
// score = Ahi*Bhi + Ahi*Blo + Alo*Bhi (split-bf16 MFMA, verified r2/r3).
// ---------------------------------------------------------------------------
static __device__ __forceinline__ void load_a(
    float4 (&buf)[4], const float* ab, int ks, int mh)
{
    const float* base = ab + (mh * 2) * 16 * VV + ks * 32;
    buf[0] = *(const float4*)(base);
    buf[1] = *(const float4*)(base + 4);
    buf[2] = *(const float4*)(base + 16 * VV);
    buf[3] = *(const float4*)(base + 16 * VV + 4);
}

__global__ __launch_bounds__(256, 3) void vq_fused(
    const float* __restrict__ x, const unsigned short* __restrict__ bfrag,
    const float* __restrict__ biasv, const float* __restrict__ proj,
    const float* __restrict__ b2,
    float* __restrict__ out0, float* __restrict__ out1,
    float* __restrict__ out2)
{
    __shared__ __align__(16) char smem[4 * 64 * 49 * 4];   // 50176 B union
    unsigned short* ldsB = (unsigned short*)smem;           // phase1 B frags
    float (*sc)[64][49] = (float (*)[64][49])smem;          // scan slabs
    v4f* pl = (v4f*)smem;                                   // phase2 proj

    const int tid  = threadIdx.x;
    const int w    = tid >> 6;
    const int lane = tid & 63;
    const int h    = lane >> 4;          // A: k-group ; C: row-group
    const int nl   = lane & 15;          // A: row     ; B/C: col
    const long t0  = (long)blockIdx.x * 256;
    const long tw  = t0 + (long)w * 64;  // this wave's first token

    // ---- stage B fragments into LDS (linear, 16B async) ----
    #pragma unroll
    for (int p = 0; p < 12; p++) {
        __builtin_amdgcn_global_load_lds(
            (const __attribute__((address_space(1))) unsigned*)
                ((const char*)bfrag + p * 4096 + tid * 16),
            (__attribute__((address_space(3))) unsigned*)
                (smem + p * 4096 + tid * 16),
            16, 0, 0);
    }

    f32x4 acc[4][3];
    #pragma unroll
    for (int m = 0; m < 4; m++)
        #pragma unroll
        for (int nt = 0; nt < 3; nt++)
            acc[m][nt] = (f32x4){0.f, 0.f, 0.f, 0.f};

    const float* ab = x + (tw + nl) * VV + h * 8;   // A fragment base

    float4 Ab[2][4];
    load_a(Ab[0], ab, 0, 0);    // prologue: stage 0 in flight

    __syncthreads();            // B copy visible (drains staging vmcnt once)

    short8 bh[3], bl[3];
    #pragma unroll
    for (int s = 0; s < 16; s++) {               // stage s = (ks = s>>1, mh = s&1)
        const int ks = s >> 1, mh = s & 1, mb = mh * 2;
        if (s < 15)
            load_a(Ab[(s + 1) & 1], ab, (s + 1) >> 1, (s + 1) & 1);
        if (mh == 0) {
            #pragma unroll
            for (int nt = 0; nt < 3; nt++) {
                bh[nt] = *(const short8*)(ldsB + (ks * 3 + nt) * 512 + lane * 8);
                bl[nt] = *(const short8*)(ldsB + 12288 + (ks * 3 + nt) * 512 + lane * 8);
            }
        }
        short8 ah0, al0, ah1, al1;
        cvt_hi_lo(Ab[mh][0], Ab[mh][1], ah0, al0);
        cvt_hi_lo(Ab[mh][2], Ab[mh][3], ah1, al1);
        #pragma unroll
        for (int nt = 0; nt < 3; nt++) {
            acc[mb][nt]     = __builtin_amdgcn_mfma_f32_16x16x32_bf16(ah0, bh[nt], acc[mb][nt], 0, 0, 0);
            acc[mb][nt]     = __builtin_amdgcn_mfma_f32_16x16x32_bf16(ah0, bl[nt], acc[mb][nt], 0, 0, 0);
            acc[mb][nt]     = __builtin_amdgcn_mfma_f32_16x16x32_bf16(al0, bh[nt], acc[mb][nt], 0, 0, 0);
            acc[mb + 1][nt] = __builtin_amdgcn_mfma_f32_16x16x32_bf16(ah1, bh[nt], acc[mb + 1][nt], 0, 0, 0);
            acc[mb + 1][nt] = __builtin_amdgcn_mfma_f32_16x16x32_bf16(ah1, bl[nt], acc[mb + 1][nt], 0, 0, 0);
            acc[mb + 1][nt] = __builtin_amdgcn_mfma_f32_16x16x32_bf16(al1, bh[nt], acc[mb + 1][nt], 0, 0, 0);
        }
    }

    // ---- scan: C layout col=lane&15, row=(lane>>4)*4+reg -> token m*16+4h+r
    __syncthreads();   // all waves done reading ldsB
    #pragma unroll
    for (int m = 0; m < 4; m++)
        #pragma unroll
        for (int nt = 0; nt < 3; nt++)
            #pragma unroll
            for (int r = 0; r < 4; r++)
                sc[w][m * 16 + h * 4 + r][nt * 16 + nl] = acc[m][nt][r];
    // per-wave slab: within-wave write->read ordered by lgkmcnt, no barrier

    float arr[NC];
    #pragma unroll
    for (int c = 0; c < NC; c++)
        arr[c] = sc[w][lane][c] + biasv[c];   // biasv: wave-uniform s_loads
    const unsigned p = argmin_pack(arr);      // token tw + lane

    // ---- phase 2: proj into LDS, stream outputs ----
    __syncthreads();                          // all scan reads done
    for (int i = tid; i < NC * 64; i += 256)
        pl[i] = ((const v4f*)proj)[i];
    __syncthreads();

    const v4f b2v = ((const v4f*)b2)[lane];

    #pragma unroll 1
    for (int tok = 0; tok < 64; tok++) {
        const unsigned pkt = (unsigned)__shfl((int)p, tok);
        v4f o = b2v;
        #pragma unroll
        for (int g = 0; g < 10; g++) {
            const int cc = CB_OFF_H[g] + (int)((pkt >> (3 * g)) & 7u);
            o += pl[cc * 64 + lane];
        }
        const long t = tw + tok;
        const v4f xv = ((const v4f*)(x + t * VV))[lane];   // L2/L3-hot re-read
        v4f s = (o - xv) + xv;   // match reference rounding for out0
        __builtin_nontemporal_store(s, (v4f*)(out0 + t * VV) + lane);

        const v4f d = xv - o;
        float pr = d.x * d.x + d.y * d.y + d.z * d.z + d.w * d.w;
        #pragma unroll
        for (int off = 32; off > 0; off >>= 1)
            pr += __shfl_xor(pr, off);
        if (lane == 0)  out1[t] = pr;
        if (lane == 32) out2[t] = pr;
    }
}

// ---------------------------------------------------------------------------
extern "C" void kernel_launch(void* const* d_in, const int* in_sizes, int n_in,
                              void* d_out, int out_size, void* d_ws, size_t ws_size,
                              hipStream_t stream) {
    const float* x0 = (const float*)d_in[0];
    const float* W1 = (const float*)d_in[1];
    const float* b1 = (const float*)d_in[2];
    const float* W2 = (const float*)d_in[3];
    const float* b2 = (const float*)d_in[4];
    const float* cb[10];
    for (int i = 0; i < 10; i++) cb[i] = (const float*)d_in[5 + i];

    float* ws = (float*)d_ws;
    unsigned short* bfrag = (unsigned short*)ws;   // 24576 ushorts = 49152 B
    float* biasv = ws + 12288;                     // 47 floats (+pad)
    float* proj  = ws + 12352;                     // 47*256 = 12032 floats

    float* out0 = (float*)d_out;
    float* out1 = out0 + (long)NN * SS * VV;  // 67108864
    float* out2 = out1 + (long)NN * SS;       // +262144

    vq_pre<<<NC + 1, 256, 0, stream>>>(W1, b1, W2,
        cb[0], cb[1], cb[2], cb[3], cb[4], cb[5], cb[6], cb[7], cb[8], cb[9],
        bfrag, biasv, proj);

    vq_fused<<<(int)(TT / 256), 256, 0, stream>>>(
        x0, bfrag, biasv, proj, b2, out0, out1, out2);
}

// Round 5
// 544.189 us; speedup vs baseline: 1.0134x; 1.0134x over previous
//
#include <hip/hip_runtime.h>

#define NN 16
#define SS 16384
#define VV 256
#define TT ((long)NN * SS)   // 262144 tokens
#define NC 47                // total codes (padded to 48 for MFMA)

static constexpr int CB_SIZES_H[10] = {3, 5, 5, 5, 5, 3, 7, 8, 3, 3};
static constexpr int CB_OFF_H[10]   = {0, 3, 8, 13, 18, 23, 26, 33, 41, 44};

typedef float v4f    __attribute__((ext_vector_type(4)));
typedef float f32x4  __attribute__((ext_vector_type(4)));
typedef short short8 __attribute__((ext_vector_type(8)));
typedef unsigned uint4e __attribute__((ext_vector_type(4)));

// ---------------------------------------------------------------------------
// Precompute (verified r2-r4). su[k][n] = -2*(W1_g^T e_c)[k] split into bf16
// hi/lo in MFMA B-fragment order; biasv; proj.
// ---------------------------------------------------------------------------
__global__ __launch_bounds__(256) void vq_pre(
    const float* __restrict__ W1, const float* __restrict__ b1,
    const float* __restrict__ W2,
    const float* __restrict__ cb0, const float* __restrict__ cb1,
    const float* __restrict__ cb2, const float* __restrict__ cb3,
    const float* __restrict__ cb4, const float* __restrict__ cb5,
    const float* __restrict__ cb6, const float* __restrict__ cb7,
    const float* __restrict__ cb8, const float* __restrict__ cb9,
    unsigned short* __restrict__ bfrag, float* __restrict__ biasv,
    float* __restrict__ proj)
{
    const int gc = blockIdx.x;           // 0..47 (47 = zero pad column)
    const int v  = threadIdx.x;          // 0..255 = k
    const int ks = v >> 5, kl = v & 31, h = kl >> 3, j = kl & 7;

    if (gc >= NC) {                      // pad column: zeros
        const int idx = (ks * 3 + 2) * 512 + (h * 16 + 15) * 8 + j;
        bfrag[idx] = 0;
        bfrag[12288 + idx] = 0;
        return;
    }

    const float* cbs[10] = {cb0, cb1, cb2, cb3, cb4, cb5, cb6, cb7, cb8, cb9};
    int g = 0;
    #pragma unroll
    for (int gg = 1; gg < 10; gg++) if (gc >= CB_OFF_H[gg]) g = gg;
    const int c = gc - CB_OFF_H[g];
    const float* e = cbs[g] + c * 16;

    float su = 0.f, pj = 0.f;
    #pragma unroll
    for (int i = 0; i < 16; i++)
        su = fmaf(W1[(long)(16 * g + i) * VV + v], e[i], su);
    const float s2 = -2.f * su;

    const unsigned u = __builtin_bit_cast(unsigned, s2);
    const float r = s2 - __builtin_bit_cast(float, u & 0xFFFF0000u);
    unsigned t = __builtin_bit_cast(unsigned, r);
    t += 0x7FFFu + ((t >> 16) & 1u);
    const int idx = (ks * 3 + (gc >> 4)) * 512 + (h * 16 + (gc & 15)) * 8 + j;
    bfrag[idx]         = (unsigned short)(u >> 16);
    bfrag[12288 + idx] = (unsigned short)(t >> 16);

    #pragma unroll
    for (int i = 0; i < 16; i++)
        pj = fmaf(e[i], W2[(long)v * 160 + i * 10 + g], pj);
    proj[gc * VV + v] = pj;

    if (v == 0) {
        float b = 0.f;
        #pragma unroll
        for (int i = 0; i < 16; i++)
            b += e[i] * (e[i] - 2.f * b1[16 * g + i]);
        biasv[gc] = b;
    }
}

// ---------------------------------------------------------------------------
static __device__ __forceinline__ void cvt_hi_lo(
    const float4 f0, const float4 f1, short8& ah, short8& al)
{
    const float f[8] = {f0.x, f0.y, f0.z, f0.w, f1.x, f1.y, f1.z, f1.w};
    uint4e H, L;
    #pragma unroll
    for (int p = 0; p < 4; p++) {
        const unsigned u0 = __builtin_bit_cast(unsigned, f[2 * p]);
        const unsigned u1 = __builtin_bit_cast(unsigned, f[2 * p + 1]);
        H[p] = (u0 >> 16) | (u1 & 0xFFFF0000u);
        const float r0 = f[2 * p]     - __builtin_bit_cast(float, u0 & 0xFFFF0000u);
        const float r1 = f[2 * p + 1] - __builtin_bit_cast(float, u1 & 0xFFFF0000u);
        unsigned t0 = __builtin_bit_cast(unsigned, r0);
        unsigned t1 = __builtin_bit_cast(unsigned, r1);
        t0 += 0x7FFFu + ((t0 >> 16) & 1u);
        t1 += 0x7FFFu + ((t1 >> 16) & 1u);
        L[p] = (t0 >> 16) | (t1 & 0xFFFF0000u);
    }
    ah = __builtin_bit_cast(short8, H);
    al = __builtin_bit_cast(short8, L);
}

static __device__ __forceinline__ unsigned argmin_pack(const float* acc) {
    unsigned p = 0;
    #pragma unroll
    for (int g = 0; g < 10; g++) {
        const int off = CB_OFF_H[g];
        const int k = CB_SIZES_H[g];
        float best = acc[off];
        int bi = 0;
        #pragma unroll
        for (int c = 1; c < 8; c++) {
            if (c < k) {
                const float vv = acc[off + c];
                if (vv < best) { best = vv; bi = c; }  // strict <: np first-min
            }
        }
        p |= (unsigned)bi << (3 * g);
    }
    return p;
}

// ---------------------------------------------------------------------------
// Fused kernel. Block = 256 threads / 256 tokens.
// LDS 50176 B union: [p1] bfrag copy -> [p1b] scan slabs -> [p2] proj.
// Phase 1: barrier-free K-loop, A prefetch DEPTH 2 (3-buffer rotation),
//          B ping-pong regs prefetched 1 ks ahead from LDS.
// Phase 2: xv prefetch depth 2 + unroll 2 to interleave token chains.
// ---------------------------------------------------------------------------
static __device__ __forceinline__ void load_a(
    float4 (&buf)[4], const float* ab, int ks, int mh)
{
    const float* base = ab + (mh * 2) * 16 * VV + ks * 32;
    buf[0] = *(const float4*)(base);
    buf[1] = *(const float4*)(base + 4);
    buf[2] = *(const float4*)(base + 16 * VV);
    buf[3] = *(const float4*)(base + 16 * VV + 4);
}

__global__ __launch_bounds__(256, 3) void vq_fused(
    const float* __restrict__ x, const unsigned short* __restrict__ bfrag,
    const float* __restrict__ biasv, const float* __restrict__ proj,
    const float* __restrict__ b2,
    float* __restrict__ out0, float* __restrict__ out1,
    float* __restrict__ out2)
{
    __shared__ __align__(16) char smem[4 * 64 * 49 * 4];   // 50176 B union
    unsigned short* ldsB = (unsigned short*)smem;           // phase1 B frags
    float (*sc)[64][49] = (float (*)[64][49])smem;          // scan slabs
    v4f* pl = (v4f*)smem;                                   // phase2 proj

    const int tid  = threadIdx.x;
    const int w    = tid >> 6;
    const int lane = tid & 63;
    const int h    = lane >> 4;          // A: k-group ; C: row-group
    const int nl   = lane & 15;          // A: row     ; B/C: col
    const long t0  = (long)blockIdx.x * 256;
    const long tw  = t0 + (long)w * 64;  // this wave's first token

    // ---- stage B fragments into LDS (linear, 16B async) ----
    #pragma unroll
    for (int p = 0; p < 12; p++) {
        __builtin_amdgcn_global_load_lds(
            (const __attribute__((address_space(1))) unsigned*)
                ((const char*)bfrag + p * 4096 + tid * 16),
            (__attribute__((address_space(3))) unsigned*)
                (smem + p * 4096 + tid * 16),
            16, 0, 0);
    }

    f32x4 acc[4][3];
    #pragma unroll
    for (int m = 0; m < 4; m++)
        #pragma unroll
        for (int nt = 0; nt < 3; nt++)
            acc[m][nt] = (f32x4){0.f, 0.f, 0.f, 0.f};

    const float* ab = x + (tw + nl) * VV + h * 8;   // A fragment base

    float4 A[3][4];
    load_a(A[0], ab, 0, 0);     // stage 0
    load_a(A[1], ab, 0, 1);     // stage 1

    __syncthreads();            // B copy visible (drains staging vmcnt once)

    short8 bh[2][3], bl[2][3];
    #pragma unroll
    for (int nt = 0; nt < 3; nt++) {    // B for ks=0
        bh[0][nt] = *(const short8*)(ldsB + nt * 512 + lane * 8);
        bl[0][nt] = *(const short8*)(ldsB + 12288 + nt * 512 + lane * 8);
    }

    #pragma unroll
    for (int s = 0; s < 16; s++) {               // stage s = (ks = s>>1, mh = s&1)
        const int ks = s >> 1, mh = s & 1, mb = mh * 2;
        if (s < 14)                               // A prefetch depth 2
            load_a(A[(s + 2) % 3], ab, (s + 2) >> 1, (s + 2) & 1);
        if (mh == 0 && ks < 7) {                  // B prefetch next ks
            const int nk = ks + 1, bb = nk & 1;
            #pragma unroll
            for (int nt = 0; nt < 3; nt++) {
                bh[bb][nt] = *(const short8*)(ldsB + (nk * 3 + nt) * 512 + lane * 8);
                bl[bb][nt] = *(const short8*)(ldsB + 12288 + (nk * 3 + nt) * 512 + lane * 8);
            }
        }
        short8 ah0, al0, ah1, al1;
        cvt_hi_lo(A[s % 3][0], A[s % 3][1], ah0, al0);
        cvt_hi_lo(A[s % 3][2], A[s % 3][3], ah1, al1);
        const int cb = ks & 1;
        #pragma unroll
        for (int nt = 0; nt < 3; nt++) {
            acc[mb][nt]     = __builtin_amdgcn_mfma_f32_16x16x32_bf16(ah0, bh[cb][nt], acc[mb][nt], 0, 0, 0);
            acc[mb][nt]     = __builtin_amdgcn_mfma_f32_16x16x32_bf16(ah0, bl[cb][nt], acc[mb][nt], 0, 0, 0);
            acc[mb][nt]     = __builtin_amdgcn_mfma_f32_16x16x32_bf16(al0, bh[cb][nt], acc[mb][nt], 0, 0, 0);
            acc[mb + 1][nt] = __builtin_amdgcn_mfma_f32_16x16x32_bf16(ah1, bh[cb][nt], acc[mb + 1][nt], 0, 0, 0);
            acc[mb + 1][nt] = __builtin_amdgcn_mfma_f32_16x16x32_bf16(ah1, bl[cb][nt], acc[mb + 1][nt], 0, 0, 0);
            acc[mb + 1][nt] = __builtin_amdgcn_mfma_f32_16x16x32_bf16(al1, bh[cb][nt], acc[mb + 1][nt], 0, 0, 0);
        }
    }

    // ---- scan: C layout col=lane&15, row=(lane>>4)*4+reg -> token m*16+4h+r
    __syncthreads();   // all waves done reading ldsB
    #pragma unroll
    for (int m = 0; m < 4; m++)
        #pragma unroll
        for (int nt = 0; nt < 3; nt++)
            #pragma unroll
            for (int r = 0; r < 4; r++)
                sc[w][m * 16 + h * 4 + r][nt * 16 + nl] = acc[m][nt][r];
    // per-wave slab: within-wave write->read ordered by lgkmcnt, no barrier

    float arr[NC];
    #pragma unroll
    for (int c = 0; c < NC; c++)
        arr[c] = sc[w][lane][c] + biasv[c];   // biasv: wave-uniform s_loads
    const unsigned p = argmin_pack(arr);      // token tw + lane

    // ---- phase 2: proj into LDS, stream outputs ----
    __syncthreads();                          // all scan reads done
    for (int i = tid; i < NC * 64; i += 256)
        pl[i] = ((const v4f*)proj)[i];
    __syncthreads();

    const v4f b2v = ((const v4f*)b2)[lane];

    // xv prefetch depth 2
    v4f xv0 = ((const v4f*)(x + tw * VV))[lane];
    v4f xv1 = ((const v4f*)(x + (tw + 1) * VV))[lane];

    #pragma unroll 2
    for (int tok = 0; tok < 64; tok++) {
        const v4f xv = xv0;
        xv0 = xv1;
        if (tok < 62)
            xv1 = ((const v4f*)(x + (tw + tok + 2) * VV))[lane];

        const unsigned pkt = (unsigned)__shfl((int)p, tok);
        v4f o = b2v;
        #pragma unroll
        for (int g = 0; g < 10; g++) {
            const int cc = CB_OFF_H[g] + (int)((pkt >> (3 * g)) & 7u);
            o += pl[cc * 64 + lane];
        }
        const long t = tw + tok;
        v4f s = (o - xv) + xv;   // match reference rounding for out0
        __builtin_nontemporal_store(s, (v4f*)(out0 + t * VV) + lane);

        const v4f d = xv - o;
        float pr = d.x * d.x + d.y * d.y + d.z * d.z + d.w * d.w;
        #pragma unroll
        for (int off = 32; off > 0; off >>= 1)
            pr += __shfl_xor(pr, off);
        if (lane == 0)  out1[t] = pr;
        if (lane == 32) out2[t] = pr;
    }
}

// ---------------------------------------------------------------------------
extern "C" void kernel_launch(void* const* d_in, const int* in_sizes, int n_in,
                              void* d_out, int out_size, void* d_ws, size_t ws_size,
                              hipStream_t stream) {
    const float* x0 = (const float*)d_in[0];
    const float* W1 = (const float*)d_in[1];
    const float* b1 = (const float*)d_in[2];
    const float* W2 = (const float*)d_in[3];
    const float* b2 = (const float*)d_in[4];
    const float* cb[10];
    for (int i = 0; i < 10; i++) cb[i] = (const float*)d_in[5 + i];

    float* ws = (float*)d_ws;
    unsigned short* bfrag = (unsigned short*)ws;   // 24576 ushorts = 49152 B
    float* biasv = ws + 12288;                     // 47 floats (+pad)
    float* proj  = ws + 12352;                     // 47*256 = 12032 floats

    float* out0 = (float*)d_out;
    float* out1 = out0 + (long)NN * SS * VV;  // 67108864
    float* out2 = out1 + (long)NN * SS;       // +262144

    vq_pre<<<NC + 1, 256, 0, stream>>>(W1, b1, W2,
        cb[0], cb[1], cb[2], cb[3], cb[4], cb[5], cb[6], cb[7], cb[8], cb[9],
        bfrag, biasv, proj);

    vq_fused<<<(int)(TT / 256), 256, 0, stream>>>(
        x0, bfrag, biasv, proj, b2, out0, out1, out2);
}